// Round 1
// baseline (1535.284 us; speedup 1.0000x reference)
//
#include <hip/hip_runtime.h>
#include <cstdint>
#include <cstddef>

// ---------------------------------------------------------------------------
// EncodeProcessDecode (MeshGraphNets-style GNN) on gfx950.
// N=20000 nodes, E=100000 edges, L=128, S=6 steps.
// Strategy: fused 2-layer MLP+LayerNorm kernel using mfma_f32_16x16x32_bf16.
//  - residual streams / LN / biases / scatter in fp32; GEMM inputs bf16.
//  - weights pre-transposed to Wt[col][k] bf16 in d_ws (prep kernel, per call).
//  - edge kernel fuses gather (senders/receivers) + scatter-add (atomics).
// ---------------------------------------------------------------------------

#define N_NODES 20000
#define N_EDGES 100000
#define LDIM    128
#define NSTEPS  6

typedef float  f32x4  __attribute__((ext_vector_type(4)));
typedef __bf16 bf16x8 __attribute__((ext_vector_type(8)));
typedef __bf16 bf16x4 __attribute__((ext_vector_type(4)));

static_assert(sizeof(__bf16) == 2, "bf16 size");

__device__ __forceinline__ void store4bf(__bf16* p, float4 v) {
  bf16x4 t;
  t.x = (__bf16)v.x; t.y = (__bf16)v.y; t.z = (__bf16)v.z; t.w = (__bf16)v.w;
  *(bf16x4*)p = t;   // 8B LDS write
}

// ---------------------------------------------------------------------------
// Prep kernel: fp32 -> bf16 transpose of all MLP weights into d_ws, + zero aggr.
// Layout of each dst: Wt[col][k] row-major, k padded to mult-of-32 (zeros).
// ---------------------------------------------------------------------------
struct PrepArgs {
  const float *s_enW1, *s_enW2, *s_eeW1, *s_eeW2;
  const float *s_beW1, *s_beW2, *s_bnW1, *s_bnW2;
  __bf16 *d_enW1, *d_enW2, *d_eeW1, *d_eeW2;
  __bf16 *d_beW1, *d_beW2, *d_bnW1, *d_bnW2;
  float* aggr;
};

__global__ __launch_bounds__(256) void prep_kernel(PrepArgs p) {
  int idx = blockIdx.x * 256 + threadIdx.x;

  if (idx < 4096) {                    // enc_n_W1t [128][32], src [11][128]
    int c = idx >> 5, k = idx & 31;
    p.d_enW1[idx] = (__bf16)((k < 11) ? p.s_enW1[k * 128 + c] : 0.f);
    return;
  }
  idx -= 4096;
  if (idx < 16384) {                   // enc_n_W2t [128][128]
    int c = idx >> 7, k = idx & 127;
    p.d_enW2[idx] = (__bf16)p.s_enW2[k * 128 + c];
    return;
  }
  idx -= 16384;
  if (idx < 4096) {                    // enc_e_W1t [128][32], src [5][128]
    int c = idx >> 5, k = idx & 31;
    p.d_eeW1[idx] = (__bf16)((k < 5) ? p.s_eeW1[k * 128 + c] : 0.f);
    return;
  }
  idx -= 4096;
  if (idx < 16384) {                   // enc_e_W2t
    int c = idx >> 7, k = idx & 127;
    p.d_eeW2[idx] = (__bf16)p.s_eeW2[k * 128 + c];
    return;
  }
  idx -= 16384;
  if (idx < 294912) {                  // blk_e_W1t [6][128][384], src [6][384][128]
    int s = idx / 49152, rem = idx % 49152;
    int c = rem / 384, k = rem % 384;
    p.d_beW1[idx] = (__bf16)p.s_beW1[(size_t)s * 49152 + k * 128 + c];
    return;
  }
  idx -= 294912;
  if (idx < 98304) {                   // blk_e_W2t [6][128][128]
    int s = idx >> 14, rem = idx & 16383;
    int c = rem >> 7, k = rem & 127;
    p.d_beW2[idx] = (__bf16)p.s_beW2[s * 16384 + k * 128 + c];
    return;
  }
  idx -= 98304;
  if (idx < 196608) {                  // blk_n_W1t [6][128][256], src [6][256][128]
    int s = idx >> 15, rem = idx & 32767;
    int c = rem >> 8, k = rem & 255;
    p.d_bnW1[idx] = (__bf16)p.s_bnW1[s * 32768 + k * 128 + c];
    return;
  }
  idx -= 196608;
  if (idx < 98304) {                   // blk_n_W2t [6][128][128]
    int s = idx >> 14, rem = idx & 16383;
    int c = rem >> 7, k = rem & 127;
    p.d_bnW2[idx] = (__bf16)p.s_bnW2[s * 16384 + k * 128 + c];
    return;
  }
  idx -= 98304;
  if (idx < 2560000) p.aggr[idx] = 0.f;   // zero aggr for step 0
}

// ---------------------------------------------------------------------------
// Fused 2-layer MLP + LayerNorm.
// MODE 0: node encoder  (x=[M,11] normalized, K1=32)  -> node_lat
// MODE 1: edge encoder  (x=[M,5]  normalized, K1=32)  -> edge_lat
// MODE 2: edge block    (gather concat, K1=384)       -> edge_lat += y; atomicAdd aggr
// MODE 3: node block    (node_lat|aggr, K1=256; zeroes aggr after read) -> node_lat += y
// Block: 64 rows x 128 cols, 256 threads (4 waves, 1 row-tile each).
// ---------------------------------------------------------------------------
struct MlpArgs {
  const float* x; const float* mean; const float* stdv;
  float* node_lat; float* edge_lat; float* aggr;
  const int* senders; const int* receivers;
  const __bf16* W1t; const __bf16* W2t;
  const float* b1; const float* b2; const float* g; const float* beta;
  int M;
};

template <int K1, int MODE>
__global__ __launch_bounds__(256, 2) void mlp2_kernel(MlpArgs a) {
  constexpr int BM  = 64;
  constexpr int K1S = K1 + 8;          // A-tile stride (bf16 elems), 16B aligned
  constexpr int HS  = LDIM + 8;        // h1 stride
  constexpr int AB0 = BM * K1S * 2;
  constexpr int H2B = BM * 129 * 4;    // h2 fp32, stride 129
  constexpr int ABY = (AB0 > H2B) ? AB0 : H2B;

  __shared__ __align__(16) char Abuf[ABY];
  __shared__ __align__(16) __bf16 H1[BM * HS];
  __shared__ float redS[BM * 4], redS2[BM * 4];
  __shared__ float muS[BM], rsS[BM];
  __shared__ int sidx[BM], ridx[BM];

  __bf16* Atile = (__bf16*)Abuf;
  float*  H2    = (float*)Abuf;

  const int tid  = threadIdx.x;
  const int row0 = blockIdx.x * BM;
  const int M    = a.M;

  // ---- stage A-tile (bf16) ----
  if constexpr (MODE == 0 || MODE == 1) {
    constexpr int KIN = (MODE == 0) ? 11 : 5;
    for (int idx = tid; idx < BM * 32; idx += 256) {
      int r = idx >> 5, c = idx & 31;
      int row = row0 + r;
      float v = 0.f;
      if (row < M && c < KIN) v = (a.x[row * KIN + c] - a.mean[c]) / a.stdv[c];
      Atile[r * K1S + c] = (__bf16)v;
    }
  } else if constexpr (MODE == 2) {
    for (int i = tid; i < BM; i += 256) {
      int e = row0 + i; if (e >= M) e = M - 1;
      sidx[i] = a.senders[e]; ridx[i] = a.receivers[e];
    }
    __syncthreads();
    for (int idx = tid; idx < BM * 32; idx += 256) {
      int r = idx >> 5, c4 = idx & 31;
      float4 v = *((const float4*)(a.node_lat + (size_t)sidx[r] * LDIM) + c4);
      store4bf(Atile + r * K1S + c4 * 4, v);
    }
    for (int idx = tid; idx < BM * 32; idx += 256) {
      int r = idx >> 5, c4 = idx & 31;
      float4 v = *((const float4*)(a.node_lat + (size_t)ridx[r] * LDIM) + c4);
      store4bf(Atile + r * K1S + 128 + c4 * 4, v);
    }
    for (int idx = tid; idx < BM * 32; idx += 256) {
      int r = idx >> 5, c4 = idx & 31;
      int e = row0 + r; if (e >= M) e = M - 1;
      float4 v = *((const float4*)(a.edge_lat + (size_t)e * LDIM) + c4);
      store4bf(Atile + r * K1S + 256 + c4 * 4, v);
    }
  } else {  // MODE 3
    for (int idx = tid; idx < BM * 32; idx += 256) {
      int r = idx >> 5, c4 = idx & 31;
      int n = row0 + r; if (n >= M) n = M - 1;
      float4 v = *((const float4*)(a.node_lat + (size_t)n * LDIM) + c4);
      store4bf(Atile + r * K1S + c4 * 4, v);
    }
    for (int idx = tid; idx < BM * 32; idx += 256) {
      int r = idx >> 5, c4 = idx & 31;
      int n = row0 + r; bool valid = (n < M); if (!valid) n = M - 1;
      float4* ap = (float4*)(a.aggr + (size_t)n * LDIM) + c4;
      float4 v = *ap;
      if (valid) *ap = make_float4(0.f, 0.f, 0.f, 0.f);  // ready for next step
      store4bf(Atile + r * K1S + 128 + c4 * 4, v);
    }
  }
  __syncthreads();

  const int lane = tid & 63;
  const int wv   = tid >> 6;
  const int l15  = lane & 15;
  const int quad = lane >> 4;
  const int arow = wv * 16 + l15;

  f32x4 acc[8];
#pragma unroll
  for (int i = 0; i < 8; ++i) acc[i] = (f32x4)(0.f);

  // ---- layer 1: [64,K1] x [K1,128] ----
  {
    const __bf16* Ab = Atile + arow * K1S + quad * 8;
#pragma unroll
    for (int kc = 0; kc < K1 / 32; ++kc) {
      bf16x8 af = *(const bf16x8*)(Ab + kc * 32);
#pragma unroll
      for (int ct = 0; ct < 8; ++ct) {
        bf16x8 bf = *(const bf16x8*)(a.W1t + (ct * 16 + l15) * K1 + kc * 32 + quad * 8);
        acc[ct] = __builtin_amdgcn_mfma_f32_16x16x32_bf16(af, bf, acc[ct], 0, 0, 0);
      }
    }
  }

  // h1 = relu(acc + b1) -> H1 (bf16)
#pragma unroll
  for (int ct = 0; ct < 8; ++ct) {
    const int col = ct * 16 + l15;
    const float bb = a.b1[col];
#pragma unroll
    for (int r = 0; r < 4; ++r) {
      float v = fmaxf(acc[ct][r] + bb, 0.f);
      H1[(wv * 16 + quad * 4 + r) * HS + col] = (__bf16)v;
    }
  }
  __syncthreads();  // all waves done with Atile; H2 overlay becomes safe

#pragma unroll
  for (int i = 0; i < 8; ++i) acc[i] = (f32x4)(0.f);

  // ---- layer 2: [64,128] x [128,128] ----
  {
    const __bf16* Hb = H1 + arow * HS + quad * 8;
#pragma unroll
    for (int kc = 0; kc < 4; ++kc) {
      bf16x8 af = *(const bf16x8*)(Hb + kc * 32);
#pragma unroll
      for (int ct = 0; ct < 8; ++ct) {
        bf16x8 bf = *(const bf16x8*)(a.W2t + (ct * 16 + l15) * LDIM + kc * 32 + quad * 8);
        acc[ct] = __builtin_amdgcn_mfma_f32_16x16x32_bf16(af, bf, acc[ct], 0, 0, 0);
      }
    }
  }

  // h2 = relu(acc + b2) -> H2 (fp32, overlays Atile)
#pragma unroll
  for (int ct = 0; ct < 8; ++ct) {
    const int col = ct * 16 + l15;
    const float bb = a.b2[col];
#pragma unroll
    for (int r = 0; r < 4; ++r) {
      float v = fmaxf(acc[ct][r] + bb, 0.f);
      H2[(wv * 16 + quad * 4 + r) * 129 + col] = v;
    }
  }
  __syncthreads();

  // ---- LayerNorm over 128 feats/row ----
  {
    const int r = tid >> 2, seg = tid & 3;
    const float* hr = H2 + r * 129 + seg * 32;
    float s = 0.f, s2 = 0.f;
#pragma unroll
    for (int c = 0; c < 32; ++c) { float v = hr[c]; s += v; s2 += v * v; }
    redS[r * 4 + seg] = s; redS2[r * 4 + seg] = s2;
  }
  __syncthreads();
  if ((tid & 3) == 0) {
    const int r = tid >> 2;
    float s  = redS[r * 4] + redS[r * 4 + 1] + redS[r * 4 + 2] + redS[r * 4 + 3];
    float s2 = redS2[r * 4] + redS2[r * 4 + 1] + redS2[r * 4 + 2] + redS2[r * 4 + 3];
    float m = s * (1.f / 128.f);
    float var = fmaxf(s2 * (1.f / 128.f) - m * m, 0.f);
    muS[r] = m; rsS[r] = rsqrtf(var + 1e-5f);
  }
  __syncthreads();

  // ---- epilogue ----
  for (int idx = tid; idx < BM * LDIM; idx += 256) {
    const int r = idx >> 7, c = idx & 127;
    const int row = row0 + r;
    if (row >= M) continue;
    float y = (H2[r * 129 + c] - muS[r]) * rsS[r] * a.g[c] + a.beta[c];
    if constexpr (MODE == 0) {
      a.node_lat[(size_t)row * LDIM + c] = y;
    } else if constexpr (MODE == 1) {
      a.edge_lat[(size_t)row * LDIM + c] = y;
    } else if constexpr (MODE == 2) {
      a.edge_lat[(size_t)row * LDIM + c] += y;                       // residual
      unsafeAtomicAdd(a.aggr + (size_t)ridx[r] * LDIM + c, y);       // scatter
    } else {
      a.node_lat[(size_t)row * LDIM + c] += y;                       // residual
    }
  }
}

// ---------------------------------------------------------------------------
// Decoder: h = swish(node_lat @ W1 + b1); dec = h @ W2 + b2; out[t,n] = dec*dt
// ---------------------------------------------------------------------------
__global__ __launch_bounds__(256) void decode_kernel(
    const float* __restrict__ node_lat,
    const float* __restrict__ W1, const float* __restrict__ b1,
    const float* __restrict__ W2, const float* __restrict__ b2,
    float* __restrict__ out) {
  __shared__ float X[64][129];
  const int n0 = blockIdx.x * 64;
  for (int idx = threadIdx.x; idx < 64 * 32; idx += 256) {
    int r = idx >> 5, c4 = idx & 31;
    int n = n0 + r; if (n >= N_NODES) n = N_NODES - 1;
    float4 v = *((const float4*)(node_lat + (size_t)n * 128) + c4);
    X[r][c4 * 4 + 0] = v.x; X[r][c4 * 4 + 1] = v.y;
    X[r][c4 * 4 + 2] = v.z; X[r][c4 * 4 + 3] = v.w;
  }
  __syncthreads();
  const int r = threadIdx.x;
  if (r < 64) {
    const int n = n0 + r;
    if (n < N_NODES) {
      float h[8];
#pragma unroll
      for (int j = 0; j < 8; ++j) h[j] = b1[j];
      for (int k = 0; k < 128; ++k) {
        float xv = X[r][k];
#pragma unroll
        for (int j = 0; j < 8; ++j) h[j] = fmaf(xv, W1[k * 8 + j], h[j]);
      }
#pragma unroll
      for (int j = 0; j < 8; ++j) h[j] = h[j] / (1.f + expf(-h[j]));  // swish
#pragma unroll
      for (int t = 0; t < 5; ++t) {
        float d = b2[t];
#pragma unroll
        for (int j = 0; j < 8; ++j) d = fmaf(h[j], W2[j * 5 + t], d);
        out[t * N_NODES + n] = d * (float)(t + 1);
      }
    }
  }
}

// ---------------------------------------------------------------------------
extern "C" void kernel_launch(void* const* d_in, const int* in_sizes, int n_in,
                              void* d_out, int out_size, void* d_ws, size_t ws_size,
                              hipStream_t stream) {
  (void)in_sizes; (void)n_in; (void)out_size; (void)ws_size;

  const float* node_features = (const float*)d_in[0];
  const float* edge_features = (const float*)d_in[1];
  const int*   senders       = (const int*)d_in[2];
  const int*   receivers     = (const int*)d_in[3];
  const float* node_mean = (const float*)d_in[4];
  const float* node_std  = (const float*)d_in[5];
  const float* edge_mean = (const float*)d_in[6];
  const float* edge_std  = (const float*)d_in[7];
  const float* enc_n_W1 = (const float*)d_in[8];
  const float* enc_n_b1 = (const float*)d_in[9];
  const float* enc_n_W2 = (const float*)d_in[10];
  const float* enc_n_b2 = (const float*)d_in[11];
  const float* enc_n_g    = (const float*)d_in[12];
  const float* enc_n_beta = (const float*)d_in[13];
  const float* enc_e_W1 = (const float*)d_in[14];
  const float* enc_e_b1 = (const float*)d_in[15];
  const float* enc_e_W2 = (const float*)d_in[16];
  const float* enc_e_b2 = (const float*)d_in[17];
  const float* enc_e_g    = (const float*)d_in[18];
  const float* enc_e_beta = (const float*)d_in[19];
  const float* blk_e_W1 = (const float*)d_in[20];
  const float* blk_e_b1 = (const float*)d_in[21];
  const float* blk_e_W2 = (const float*)d_in[22];
  const float* blk_e_b2 = (const float*)d_in[23];
  const float* blk_e_g    = (const float*)d_in[24];
  const float* blk_e_beta = (const float*)d_in[25];
  const float* blk_n_W1 = (const float*)d_in[26];
  const float* blk_n_b1 = (const float*)d_in[27];
  const float* blk_n_W2 = (const float*)d_in[28];
  const float* blk_n_b2 = (const float*)d_in[29];
  const float* blk_n_g    = (const float*)d_in[30];
  const float* blk_n_beta = (const float*)d_in[31];
  const float* dec_W1 = (const float*)d_in[32];
  const float* dec_b1 = (const float*)d_in[33];
  const float* dec_W2 = (const float*)d_in[34];
  const float* dec_b2 = (const float*)d_in[35];

  // ---- workspace layout (bytes) ----
  char* ws = (char*)d_ws;
  float* node_lat = (float*)(ws);                  // 20000*128*4 = 10,240,000
  float* edge_lat = (float*)(ws + 10240000);       // 100000*128*4 = 51,200,000
  float* aggr     = (float*)(ws + 61440000);       // 20000*128*4 = 10,240,000
  __bf16* wb      = (__bf16*)(ws + 71680000);      // bf16 weights, 1,458,176 B
  __bf16* enW1t = wb;                    // 128*32
  __bf16* enW2t = enW1t + 4096;          // 128*128
  __bf16* eeW1t = enW2t + 16384;         // 128*32
  __bf16* eeW2t = eeW1t + 4096;          // 128*128
  __bf16* beW1t = eeW2t + 16384;         // 6*128*384
  __bf16* beW2t = beW1t + 6 * 49152;     // 6*128*128
  __bf16* bnW1t = beW2t + 6 * 16384;     // 6*128*256
  __bf16* bnW2t = bnW1t + 6 * 32768;     // 6*128*128

  // ---- prep: weight transpose/convert + zero aggr ----
  PrepArgs pa;
  pa.s_enW1 = enc_n_W1; pa.s_enW2 = enc_n_W2; pa.s_eeW1 = enc_e_W1; pa.s_eeW2 = enc_e_W2;
  pa.s_beW1 = blk_e_W1; pa.s_beW2 = blk_e_W2; pa.s_bnW1 = blk_n_W1; pa.s_bnW2 = blk_n_W2;
  pa.d_enW1 = enW1t; pa.d_enW2 = enW2t; pa.d_eeW1 = eeW1t; pa.d_eeW2 = eeW2t;
  pa.d_beW1 = beW1t; pa.d_beW2 = beW2t; pa.d_bnW1 = bnW1t; pa.d_bnW2 = bnW2t;
  pa.aggr = aggr;
  prep_kernel<<<12848, 256, 0, stream>>>(pa);   // 3,289,088 total elems

  const int NODE_BLOCKS = (N_NODES + 63) / 64;   // 313
  const int EDGE_BLOCKS = (N_EDGES + 63) / 64;   // 1563

  MlpArgs base;
  base.node_lat = node_lat; base.edge_lat = edge_lat; base.aggr = aggr;
  base.senders = senders; base.receivers = receivers;
  base.x = nullptr; base.mean = nullptr; base.stdv = nullptr;

  // ---- encoders ----
  {
    MlpArgs a = base;
    a.x = node_features; a.mean = node_mean; a.stdv = node_std;
    a.W1t = enW1t; a.W2t = enW2t;
    a.b1 = enc_n_b1; a.b2 = enc_n_b2; a.g = enc_n_g; a.beta = enc_n_beta;
    a.M = N_NODES;
    mlp2_kernel<32, 0><<<NODE_BLOCKS, 256, 0, stream>>>(a);
  }
  {
    MlpArgs a = base;
    a.x = edge_features; a.mean = edge_mean; a.stdv = edge_std;
    a.W1t = eeW1t; a.W2t = eeW2t;
    a.b1 = enc_e_b1; a.b2 = enc_e_b2; a.g = enc_e_g; a.beta = enc_e_beta;
    a.M = N_EDGES;
    mlp2_kernel<32, 1><<<EDGE_BLOCKS, 256, 0, stream>>>(a);
  }

  // ---- message-passing steps ----
  for (int i = 0; i < NSTEPS; ++i) {
    {
      MlpArgs a = base;
      a.W1t = beW1t + (size_t)i * 49152; a.W2t = beW2t + (size_t)i * 16384;
      a.b1 = blk_e_b1 + i * 128; a.b2 = blk_e_b2 + i * 128;
      a.g = blk_e_g + i * 128; a.beta = blk_e_beta + i * 128;
      a.M = N_EDGES;
      mlp2_kernel<384, 2><<<EDGE_BLOCKS, 256, 0, stream>>>(a);
    }
    {
      MlpArgs a = base;
      a.W1t = bnW1t + (size_t)i * 32768; a.W2t = bnW2t + (size_t)i * 16384;
      a.b1 = blk_n_b1 + i * 128; a.b2 = blk_n_b2 + i * 128;
      a.g = blk_n_g + i * 128; a.beta = blk_n_beta + i * 128;
      a.M = N_NODES;
      mlp2_kernel<256, 3><<<NODE_BLOCKS, 256, 0, stream>>>(a);
    }
  }

  // ---- decoder ----
  decode_kernel<<<NODE_BLOCKS, 256, 0, stream>>>(
      node_lat, dec_W1, dec_b1, dec_W2, dec_b2, (float*)d_out);
}

// Round 2
// 1311.570 us; speedup vs baseline: 1.1706x; 1.1706x over previous
//
#include <hip/hip_runtime.h>
#include <cstdint>
#include <cstddef>

// ---------------------------------------------------------------------------
// EncodeProcessDecode (MeshGraphNets-style GNN) on gfx950.
// N=20000 nodes, E=100000 edges, L=128, S=6 steps.
// Round 2: wave-local fused MLP pipeline — ZERO block barriers.
//  - A-fragments loaded straight from global (fp32->bf16 in-register).
//  - h1 transposed through a per-wave LDS strip (wave-local, no barrier).
//  - LayerNorm in registers via 16-lane shuffle reduction.
//  - edge kernel fuses gather + residual + scatter-add (HW f32 atomics).
// ---------------------------------------------------------------------------

#define N_NODES 20000
#define N_EDGES 100000
#define LDIM    128
#define NSTEPS  6

typedef float  f32x4  __attribute__((ext_vector_type(4)));
typedef __bf16 bf16x8 __attribute__((ext_vector_type(8)));

// load 8 consecutive fp32, round to bf16x8 (one MFMA A-frag chunk)
__device__ __forceinline__ bf16x8 cvt8(const float* p) {
  float4 u = *(const float4*)p;
  float4 v = *(const float4*)(p + 4);
  bf16x8 o;
  o[0] = (__bf16)u.x; o[1] = (__bf16)u.y; o[2] = (__bf16)u.z; o[3] = (__bf16)u.w;
  o[4] = (__bf16)v.x; o[5] = (__bf16)v.y; o[6] = (__bf16)v.z; o[7] = (__bf16)v.w;
  return o;
}

// ---------------------------------------------------------------------------
// Prep kernel: fp32 -> bf16 transpose of all MLP weights into d_ws, + zero aggr.
// Layout of each dst: Wt[col][k] row-major, k padded to mult-of-32 (zeros).
// ---------------------------------------------------------------------------
struct PrepArgs {
  const float *s_enW1, *s_enW2, *s_eeW1, *s_eeW2;
  const float *s_beW1, *s_beW2, *s_bnW1, *s_bnW2;
  __bf16 *d_enW1, *d_enW2, *d_eeW1, *d_eeW2;
  __bf16 *d_beW1, *d_beW2, *d_bnW1, *d_bnW2;
  float* aggr;
};

__global__ __launch_bounds__(256) void prep_kernel(PrepArgs p) {
  int idx = blockIdx.x * 256 + threadIdx.x;

  if (idx < 4096) {                    // enc_n_W1t [128][32], src [11][128]
    int c = idx >> 5, k = idx & 31;
    p.d_enW1[idx] = (__bf16)((k < 11) ? p.s_enW1[k * 128 + c] : 0.f);
    return;
  }
  idx -= 4096;
  if (idx < 16384) {                   // enc_n_W2t [128][128]
    int c = idx >> 7, k = idx & 127;
    p.d_enW2[idx] = (__bf16)p.s_enW2[k * 128 + c];
    return;
  }
  idx -= 16384;
  if (idx < 4096) {                    // enc_e_W1t [128][32], src [5][128]
    int c = idx >> 5, k = idx & 31;
    p.d_eeW1[idx] = (__bf16)((k < 5) ? p.s_eeW1[k * 128 + c] : 0.f);
    return;
  }
  idx -= 4096;
  if (idx < 16384) {                   // enc_e_W2t
    int c = idx >> 7, k = idx & 127;
    p.d_eeW2[idx] = (__bf16)p.s_eeW2[k * 128 + c];
    return;
  }
  idx -= 16384;
  if (idx < 294912) {                  // blk_e_W1t [6][128][384], src [6][384][128]
    int s = idx / 49152, rem = idx % 49152;
    int c = rem / 384, k = rem % 384;
    p.d_beW1[idx] = (__bf16)p.s_beW1[(size_t)s * 49152 + k * 128 + c];
    return;
  }
  idx -= 294912;
  if (idx < 98304) {                   // blk_e_W2t [6][128][128]
    int s = idx >> 14, rem = idx & 16383;
    int c = rem >> 7, k = rem & 127;
    p.d_beW2[idx] = (__bf16)p.s_beW2[s * 16384 + k * 128 + c];
    return;
  }
  idx -= 98304;
  if (idx < 196608) {                  // blk_n_W1t [6][128][256], src [6][256][128]
    int s = idx >> 15, rem = idx & 32767;
    int c = rem >> 8, k = rem & 255;
    p.d_bnW1[idx] = (__bf16)p.s_bnW1[s * 32768 + k * 128 + c];
    return;
  }
  idx -= 196608;
  if (idx < 98304) {                   // blk_n_W2t [6][128][128]
    int s = idx >> 14, rem = idx & 16383;
    int c = rem >> 7, k = rem & 127;
    p.d_bnW2[idx] = (__bf16)p.s_bnW2[s * 16384 + k * 128 + c];
    return;
  }
  idx -= 98304;
  if (idx < 2560000) p.aggr[idx] = 0.f;   // zero aggr for step 0
}

// ---------------------------------------------------------------------------
// Fused 2-layer MLP + LayerNorm, wave-local (no __syncthreads).
// Each wave handles 16 rows end-to-end. Block = 4 waves = 64 rows.
// MODE 0: node encoder  (x=[M,11] normalized, K1=32)  -> node_lat
// MODE 1: edge encoder  (x=[M,5]  normalized, K1=32)  -> edge_lat
// MODE 2: edge block    (gather concat, K1=384)       -> edge_lat += y; atomicAdd aggr
// MODE 3: node block    (node_lat|aggr, K1=256; zeroes aggr after read) -> node_lat += y
// ---------------------------------------------------------------------------
struct MlpArgs {
  const float* x; const float* mean; const float* stdv;
  float* node_lat; float* edge_lat; float* aggr;
  const int* senders; const int* receivers;
  const __bf16* W1t; const __bf16* W2t;
  const float* b1; const float* b2; const float* g; const float* beta;
  int M;
};

template <int K1, int MODE>
__global__ __launch_bounds__(256, 3) void mlp2_kernel(MlpArgs a) {
  constexpr int NKC = K1 / 32;          // A-frag chunks for layer 1
  constexpr int HS  = 136;              // h1 LDS stride (bf16): 272B rows, 16B aligned

  __shared__ __align__(16) __bf16 H1[4 * 16 * HS];   // 17408 B, per-wave strips

  const int tid   = threadIdx.x;
  const int lane  = tid & 63;
  const int wv    = tid >> 6;
  const int l15   = lane & 15;
  const int quad  = lane >> 4;
  const int M     = a.M;
  const int rbase = blockIdx.x * 64 + wv * 16;       // wave's first row
  const int arow  = rbase + l15;                     // row this lane stages
  const int arow_c = (arow < M) ? arow : (M - 1);

  __bf16* h1w = H1 + wv * 16 * HS;

  // ---- stage A fragments straight from global (bf16 in registers) ----
  bf16x8 afrag[NKC];
  if constexpr (MODE == 0 || MODE == 1) {
    constexpr int KIN = (MODE == 0) ? 11 : 5;
    const float* xr = a.x + (size_t)arow_c * KIN;
#pragma unroll
    for (int j = 0; j < 8; ++j) {
      int c = quad * 8 + j;
      float v = (c < KIN) ? (xr[c] - a.mean[c]) / a.stdv[c] : 0.f;
      afrag[0][j] = (__bf16)v;
    }
  } else if constexpr (MODE == 2) {
    const int s = a.senders[arow_c];
    const int r = a.receivers[arow_c];
    const float* pS = a.node_lat + (size_t)s * LDIM + quad * 8;
    const float* pR = a.node_lat + (size_t)r * LDIM + quad * 8;
    const float* pE = a.edge_lat + (size_t)arow_c * LDIM + quad * 8;
#pragma unroll
    for (int kc = 0; kc < 4; ++kc) afrag[kc]     = cvt8(pS + kc * 32);
#pragma unroll
    for (int kc = 0; kc < 4; ++kc) afrag[4 + kc] = cvt8(pR + kc * 32);
#pragma unroll
    for (int kc = 0; kc < 4; ++kc) afrag[8 + kc] = cvt8(pE + kc * 32);
  } else {  // MODE 3: [node_lat | aggr], zero aggr after read (owner lane only)
    const float* pN = a.node_lat + (size_t)arow_c * LDIM + quad * 8;
    float*       pA = a.aggr     + (size_t)arow_c * LDIM + quad * 8;
#pragma unroll
    for (int kc = 0; kc < 4; ++kc) afrag[kc] = cvt8(pN + kc * 32);
#pragma unroll
    for (int kc = 0; kc < 4; ++kc) {
      float4 u = *(const float4*)(pA + kc * 32);
      float4 v = *(const float4*)(pA + kc * 32 + 4);
      bf16x8 o;
      o[0] = (__bf16)u.x; o[1] = (__bf16)u.y; o[2] = (__bf16)u.z; o[3] = (__bf16)u.w;
      o[4] = (__bf16)v.x; o[5] = (__bf16)v.y; o[6] = (__bf16)v.z; o[7] = (__bf16)v.w;
      afrag[4 + kc] = o;
      if (arow < M) {   // true owner zeroes; clamped duplicates must not race
        *(float4*)(pA + kc * 32)     = make_float4(0.f, 0.f, 0.f, 0.f);
        *(float4*)(pA + kc * 32 + 4) = make_float4(0.f, 0.f, 0.f, 0.f);
      }
    }
  }

  // ---- layer 1: [16,K1] x [K1,128] per wave ----
  f32x4 acc[8];
#pragma unroll
  for (int i = 0; i < 8; ++i) acc[i] = (f32x4)(0.f);
#pragma unroll
  for (int kc = 0; kc < NKC; ++kc) {
#pragma unroll
    for (int ct = 0; ct < 8; ++ct) {
      bf16x8 bf = *(const bf16x8*)(a.W1t + (ct * 16 + l15) * K1 + kc * 32 + quad * 8);
      acc[ct] = __builtin_amdgcn_mfma_f32_16x16x32_bf16(afrag[kc], bf, acc[ct], 0, 0, 0);
    }
  }

  // ---- h1 = relu(acc+b1) -> per-wave LDS strip (C/D layout -> row-major) ----
#pragma unroll
  for (int ct = 0; ct < 8; ++ct) {
    const float bb = a.b1[ct * 16 + l15];
#pragma unroll
    for (int rr = 0; rr < 4; ++rr) {
      float v = fmaxf(acc[ct][rr] + bb, 0.f);
      h1w[(quad * 4 + rr) * HS + ct * 16 + l15] = (__bf16)v;
    }
  }
  // same-wave DS ordering: write->read in order; compiler inserts lgkmcnt waits.

  // ---- layer 2: [16,128] x [128,128] per wave ----
#pragma unroll
  for (int i = 0; i < 8; ++i) acc[i] = (f32x4)(0.f);
#pragma unroll
  for (int kc = 0; kc < 4; ++kc) {
    bf16x8 af = *(const bf16x8*)(h1w + l15 * HS + kc * 32 + quad * 8);
#pragma unroll
    for (int ct = 0; ct < 8; ++ct) {
      bf16x8 bf = *(const bf16x8*)(a.W2t + (ct * 16 + l15) * LDIM + kc * 32 + quad * 8);
      acc[ct] = __builtin_amdgcn_mfma_f32_16x16x32_bf16(af, bf, acc[ct], 0, 0, 0);
    }
  }

  // ---- h2 = relu(acc+b2), LayerNorm in registers (shuffle over 16 lanes) ----
#pragma unroll
  for (int ct = 0; ct < 8; ++ct) {
    const float bb = a.b2[ct * 16 + l15];
#pragma unroll
    for (int rr = 0; rr < 4; ++rr)
      acc[ct][rr] = fmaxf(acc[ct][rr] + bb, 0.f);
  }

  float mu[4], rs[4];
#pragma unroll
  for (int rr = 0; rr < 4; ++rr) {
    float s = 0.f, s2 = 0.f;
#pragma unroll
    for (int ct = 0; ct < 8; ++ct) { float v = acc[ct][rr]; s += v; s2 += v * v; }
    s  += __shfl_xor(s, 1);  s2 += __shfl_xor(s2, 1);
    s  += __shfl_xor(s, 2);  s2 += __shfl_xor(s2, 2);
    s  += __shfl_xor(s, 4);  s2 += __shfl_xor(s2, 4);
    s  += __shfl_xor(s, 8);  s2 += __shfl_xor(s2, 8);
    float m = s * (1.f / 128.f);
    float var = fmaxf(s2 * (1.f / 128.f) - m * m, 0.f);
    mu[rr] = m; rs[rr] = rsqrtf(var + 1e-5f);
  }

  float gv[8], bev[8];
#pragma unroll
  for (int ct = 0; ct < 8; ++ct) {
    gv[ct]  = a.g[ct * 16 + l15];
    bev[ct] = a.beta[ct * 16 + l15];
  }

  // ---- epilogue (per-wave, guarded rows) ----
#pragma unroll
  for (int rr = 0; rr < 4; ++rr) {
    const int row = rbase + quad * 4 + rr;
    if (row >= M) continue;
    if constexpr (MODE == 2) {
      const int ridx = a.receivers[row];
#pragma unroll
      for (int ct = 0; ct < 8; ++ct) {
        const int col = ct * 16 + l15;
        float y = (acc[ct][rr] - mu[rr]) * rs[rr] * gv[ct] + bev[ct];
        a.edge_lat[(size_t)row * LDIM + col] += y;                 // residual
        unsafeAtomicAdd(a.aggr + (size_t)ridx * LDIM + col, y);    // scatter
      }
    } else {
#pragma unroll
      for (int ct = 0; ct < 8; ++ct) {
        const int col = ct * 16 + l15;
        float y = (acc[ct][rr] - mu[rr]) * rs[rr] * gv[ct] + bev[ct];
        if constexpr (MODE == 0)      a.node_lat[(size_t)row * LDIM + col] = y;
        else if constexpr (MODE == 1) a.edge_lat[(size_t)row * LDIM + col] = y;
        else                          a.node_lat[(size_t)row * LDIM + col] += y;
      }
    }
  }
}

// ---------------------------------------------------------------------------
// Decoder: h = swish(node_lat @ W1 + b1); dec = h @ W2 + b2; out[t,n] = dec*dt
// ---------------------------------------------------------------------------
__global__ __launch_bounds__(256) void decode_kernel(
    const float* __restrict__ node_lat,
    const float* __restrict__ W1, const float* __restrict__ b1,
    const float* __restrict__ W2, const float* __restrict__ b2,
    float* __restrict__ out) {
  __shared__ float X[64][129];
  const int n0 = blockIdx.x * 64;
  for (int idx = threadIdx.x; idx < 64 * 32; idx += 256) {
    int r = idx >> 5, c4 = idx & 31;
    int n = n0 + r; if (n >= N_NODES) n = N_NODES - 1;
    float4 v = *((const float4*)(node_lat + (size_t)n * 128) + c4);
    X[r][c4 * 4 + 0] = v.x; X[r][c4 * 4 + 1] = v.y;
    X[r][c4 * 4 + 2] = v.z; X[r][c4 * 4 + 3] = v.w;
  }
  __syncthreads();
  const int r = threadIdx.x;
  if (r < 64) {
    const int n = n0 + r;
    if (n < N_NODES) {
      float h[8];
#pragma unroll
      for (int j = 0; j < 8; ++j) h[j] = b1[j];
      for (int k = 0; k < 128; ++k) {
        float xv = X[r][k];
#pragma unroll
        for (int j = 0; j < 8; ++j) h[j] = fmaf(xv, W1[k * 8 + j], h[j]);
      }
#pragma unroll
      for (int j = 0; j < 8; ++j) h[j] = h[j] / (1.f + expf(-h[j]));  // swish
#pragma unroll
      for (int t = 0; t < 5; ++t) {
        float d = b2[t];
#pragma unroll
        for (int j = 0; j < 8; ++j) d = fmaf(h[j], W2[j * 5 + t], d);
        out[t * N_NODES + n] = d * (float)(t + 1);
      }
    }
  }
}

// ---------------------------------------------------------------------------
extern "C" void kernel_launch(void* const* d_in, const int* in_sizes, int n_in,
                              void* d_out, int out_size, void* d_ws, size_t ws_size,
                              hipStream_t stream) {
  (void)in_sizes; (void)n_in; (void)out_size; (void)ws_size;

  const float* node_features = (const float*)d_in[0];
  const float* edge_features = (const float*)d_in[1];
  const int*   senders       = (const int*)d_in[2];
  const int*   receivers     = (const int*)d_in[3];
  const float* node_mean = (const float*)d_in[4];
  const float* node_std  = (const float*)d_in[5];
  const float* edge_mean = (const float*)d_in[6];
  const float* edge_std  = (const float*)d_in[7];
  const float* enc_n_W1 = (const float*)d_in[8];
  const float* enc_n_b1 = (const float*)d_in[9];
  const float* enc_n_W2 = (const float*)d_in[10];
  const float* enc_n_b2 = (const float*)d_in[11];
  const float* enc_n_g    = (const float*)d_in[12];
  const float* enc_n_beta = (const float*)d_in[13];
  const float* enc_e_W1 = (const float*)d_in[14];
  const float* enc_e_b1 = (const float*)d_in[15];
  const float* enc_e_W2 = (const float*)d_in[16];
  const float* enc_e_b2 = (const float*)d_in[17];
  const float* enc_e_g    = (const float*)d_in[18];
  const float* enc_e_beta = (const float*)d_in[19];
  const float* blk_e_W1 = (const float*)d_in[20];
  const float* blk_e_b1 = (const float*)d_in[21];
  const float* blk_e_W2 = (const float*)d_in[22];
  const float* blk_e_b2 = (const float*)d_in[23];
  const float* blk_e_g    = (const float*)d_in[24];
  const float* blk_e_beta = (const float*)d_in[25];
  const float* blk_n_W1 = (const float*)d_in[26];
  const float* blk_n_b1 = (const float*)d_in[27];
  const float* blk_n_W2 = (const float*)d_in[28];
  const float* blk_n_b2 = (const float*)d_in[29];
  const float* blk_n_g    = (const float*)d_in[30];
  const float* blk_n_beta = (const float*)d_in[31];
  const float* dec_W1 = (const float*)d_in[32];
  const float* dec_b1 = (const float*)d_in[33];
  const float* dec_W2 = (const float*)d_in[34];
  const float* dec_b2 = (const float*)d_in[35];

  // ---- workspace layout (bytes) ----
  char* ws = (char*)d_ws;
  float* node_lat = (float*)(ws);                  // 20000*128*4 = 10,240,000
  float* edge_lat = (float*)(ws + 10240000);       // 100000*128*4 = 51,200,000
  float* aggr     = (float*)(ws + 61440000);       // 20000*128*4 = 10,240,000
  __bf16* wb      = (__bf16*)(ws + 71680000);      // bf16 weights, 1,458,176 B
  __bf16* enW1t = wb;                    // 128*32
  __bf16* enW2t = enW1t + 4096;          // 128*128
  __bf16* eeW1t = enW2t + 16384;         // 128*32
  __bf16* eeW2t = eeW1t + 4096;          // 128*128
  __bf16* beW1t = eeW2t + 16384;         // 6*128*384
  __bf16* beW2t = beW1t + 6 * 49152;     // 6*128*128
  __bf16* bnW1t = beW2t + 6 * 16384;     // 6*128*256
  __bf16* bnW2t = bnW1t + 6 * 32768;     // 6*128*128

  // ---- prep: weight transpose/convert + zero aggr ----
  PrepArgs pa;
  pa.s_enW1 = enc_n_W1; pa.s_enW2 = enc_n_W2; pa.s_eeW1 = enc_e_W1; pa.s_eeW2 = enc_e_W2;
  pa.s_beW1 = blk_e_W1; pa.s_beW2 = blk_e_W2; pa.s_bnW1 = blk_n_W1; pa.s_bnW2 = blk_n_W2;
  pa.d_enW1 = enW1t; pa.d_enW2 = enW2t; pa.d_eeW1 = eeW1t; pa.d_eeW2 = eeW2t;
  pa.d_beW1 = beW1t; pa.d_beW2 = beW2t; pa.d_bnW1 = bnW1t; pa.d_bnW2 = bnW2t;
  pa.aggr = aggr;
  prep_kernel<<<12848, 256, 0, stream>>>(pa);   // 3,289,088 total elems

  const int NODE_BLOCKS = (N_NODES + 63) / 64;   // 313
  const int EDGE_BLOCKS = (N_EDGES + 63) / 64;   // 1563

  MlpArgs base;
  base.node_lat = node_lat; base.edge_lat = edge_lat; base.aggr = aggr;
  base.senders = senders; base.receivers = receivers;
  base.x = nullptr; base.mean = nullptr; base.stdv = nullptr;

  // ---- encoders ----
  {
    MlpArgs a = base;
    a.x = node_features; a.mean = node_mean; a.stdv = node_std;
    a.W1t = enW1t; a.W2t = enW2t;
    a.b1 = enc_n_b1; a.b2 = enc_n_b2; a.g = enc_n_g; a.beta = enc_n_beta;
    a.M = N_NODES;
    mlp2_kernel<32, 0><<<NODE_BLOCKS, 256, 0, stream>>>(a);
  }
  {
    MlpArgs a = base;
    a.x = edge_features; a.mean = edge_mean; a.stdv = edge_std;
    a.W1t = eeW1t; a.W2t = eeW2t;
    a.b1 = enc_e_b1; a.b2 = enc_e_b2; a.g = enc_e_g; a.beta = enc_e_beta;
    a.M = N_EDGES;
    mlp2_kernel<32, 1><<<EDGE_BLOCKS, 256, 0, stream>>>(a);
  }

  // ---- message-passing steps ----
  for (int i = 0; i < NSTEPS; ++i) {
    {
      MlpArgs a = base;
      a.W1t = beW1t + (size_t)i * 49152; a.W2t = beW2t + (size_t)i * 16384;
      a.b1 = blk_e_b1 + i * 128; a.b2 = blk_e_b2 + i * 128;
      a.g = blk_e_g + i * 128; a.beta = blk_e_beta + i * 128;
      a.M = N_EDGES;
      mlp2_kernel<384, 2><<<EDGE_BLOCKS, 256, 0, stream>>>(a);
    }
    {
      MlpArgs a = base;
      a.W1t = bnW1t + (size_t)i * 32768; a.W2t = bnW2t + (size_t)i * 16384;
      a.b1 = blk_n_b1 + i * 128; a.b2 = blk_n_b2 + i * 128;
      a.g = blk_n_g + i * 128; a.beta = blk_n_beta + i * 128;
      a.M = N_NODES;
      mlp2_kernel<256, 3><<<NODE_BLOCKS, 256, 0, stream>>>(a);
    }
  }

  // ---- decoder ----
  decode_kernel<<<NODE_BLOCKS, 256, 0, stream>>>(
      node_lat, dec_W1, dec_b1, dec_W2, dec_b2, (float*)d_out);
}

// Round 3
// 1239.905 us; speedup vs baseline: 1.2382x; 1.0578x over previous
//
#include <hip/hip_runtime.h>
#include <cstdint>
#include <cstddef>

// ---------------------------------------------------------------------------
// EncodeProcessDecode (MeshGraphNets-style GNN) on gfx950.
// N=20000 nodes, E=100000 edges, L=128, S=6 steps.
// Round 3: atomic-free aggregation.
//  - edge kernel writes new_e (bf16) instead of 12.8M memory-side f32 atomics
//    (r2 counters: 48.8 MB of WRITE_SIZE was atomic RMW traffic -> serializer).
//  - node kernel CSR-gathers new_e and sums aggr in registers.
//  - CSR (row_ptr/edge_list) rebuilt every call in prep (graph-capture safe).
//  - wave-local MLP pipeline (no block barriers), LN via 16-lane shuffles.
// ---------------------------------------------------------------------------

#define N_NODES 20000
#define N_EDGES 100000
#define LDIM    128
#define NSTEPS  6

typedef float  f32x4  __attribute__((ext_vector_type(4)));
typedef __bf16 bf16x8 __attribute__((ext_vector_type(8)));

// load 8 consecutive fp32, round to bf16x8 (one MFMA A-frag chunk)
__device__ __forceinline__ bf16x8 cvt8(const float* p) {
  float4 u = *(const float4*)p;
  float4 v = *(const float4*)(p + 4);
  bf16x8 o;
  o[0] = (__bf16)u.x; o[1] = (__bf16)u.y; o[2] = (__bf16)u.z; o[3] = (__bf16)u.w;
  o[4] = (__bf16)v.x; o[5] = (__bf16)v.y; o[6] = (__bf16)v.z; o[7] = (__bf16)v.w;
  return o;
}

// ---------------------------------------------------------------------------
// Prep kernel: fp32 -> bf16 transpose of all MLP weights into d_ws,
// + zero CSR counts. Layout of each dst: Wt[col][k] row-major, k padded.
// ---------------------------------------------------------------------------
struct PrepArgs {
  const float *s_enW1, *s_enW2, *s_eeW1, *s_eeW2;
  const float *s_beW1, *s_beW2, *s_bnW1, *s_bnW2;
  __bf16 *d_enW1, *d_enW2, *d_eeW1, *d_eeW2;
  __bf16 *d_beW1, *d_beW2, *d_bnW1, *d_bnW2;
  int* counts;
};

__global__ __launch_bounds__(256) void prep_kernel(PrepArgs p) {
  int idx = blockIdx.x * 256 + threadIdx.x;

  if (idx < 4096) {                    // enc_n_W1t [128][32], src [11][128]
    int c = idx >> 5, k = idx & 31;
    p.d_enW1[idx] = (__bf16)((k < 11) ? p.s_enW1[k * 128 + c] : 0.f);
    return;
  }
  idx -= 4096;
  if (idx < 16384) {                   // enc_n_W2t [128][128]
    int c = idx >> 7, k = idx & 127;
    p.d_enW2[idx] = (__bf16)p.s_enW2[k * 128 + c];
    return;
  }
  idx -= 16384;
  if (idx < 4096) {                    // enc_e_W1t [128][32], src [5][128]
    int c = idx >> 5, k = idx & 31;
    p.d_eeW1[idx] = (__bf16)((k < 5) ? p.s_eeW1[k * 128 + c] : 0.f);
    return;
  }
  idx -= 4096;
  if (idx < 16384) {                   // enc_e_W2t
    int c = idx >> 7, k = idx & 127;
    p.d_eeW2[idx] = (__bf16)p.s_eeW2[k * 128 + c];
    return;
  }
  idx -= 16384;
  if (idx < 294912) {                  // blk_e_W1t [6][128][384], src [6][384][128]
    int s = idx / 49152, rem = idx % 49152;
    int c = rem / 384, k = rem % 384;
    p.d_beW1[idx] = (__bf16)p.s_beW1[(size_t)s * 49152 + k * 128 + c];
    return;
  }
  idx -= 294912;
  if (idx < 98304) {                   // blk_e_W2t [6][128][128]
    int s = idx >> 14, rem = idx & 16383;
    int c = rem >> 7, k = rem & 127;
    p.d_beW2[idx] = (__bf16)p.s_beW2[s * 16384 + k * 128 + c];
    return;
  }
  idx -= 98304;
  if (idx < 196608) {                  // blk_n_W1t [6][128][256], src [6][256][128]
    int s = idx >> 15, rem = idx & 32767;
    int c = rem >> 8, k = rem & 255;
    p.d_bnW1[idx] = (__bf16)p.s_bnW1[s * 32768 + k * 128 + c];
    return;
  }
  idx -= 196608;
  if (idx < 98304) {                   // blk_n_W2t [6][128][128]
    int s = idx >> 14, rem = idx & 16383;
    int c = rem >> 7, k = rem & 127;
    p.d_bnW2[idx] = (__bf16)p.s_bnW2[s * 16384 + k * 128 + c];
    return;
  }
  idx -= 98304;
  if (idx < N_NODES) p.counts[idx] = 0;   // zero CSR histogram
}

// ---- CSR build: histogram -> scan -> fill -------------------------------
__global__ __launch_bounds__(256) void hist_kernel(const int* __restrict__ recv,
                                                   int* __restrict__ counts) {
  int e = blockIdx.x * 256 + threadIdx.x;
  if (e < N_EDGES) atomicAdd(&counts[recv[e]], 1);
}

__global__ __launch_bounds__(1024) void scan_kernel(const int* __restrict__ counts,
                                                    int* __restrict__ row_ptr,
                                                    int* __restrict__ cursor) {
  __shared__ int part[1024];
  const int t = threadIdx.x;
  const int base = t * 20;
  int local[20];
  int s = 0;
#pragma unroll
  for (int i = 0; i < 20; ++i) {
    int idx = base + i;
    int v = (idx < N_NODES) ? counts[idx] : 0;
    local[i] = s;                      // exclusive within chunk
    s += v;
  }
  part[t] = s;
  __syncthreads();
  for (int off = 1; off < 1024; off <<= 1) {
    int add = (t >= off) ? part[t - off] : 0;
    __syncthreads();
    part[t] += add;
    __syncthreads();
  }
  const int excl = part[t] - s;        // exclusive prefix of this chunk
#pragma unroll
  for (int i = 0; i < 20; ++i) {
    int idx = base + i;
    if (idx < N_NODES) {
      int v = excl + local[i];
      row_ptr[idx] = v;
      cursor[idx]  = v;
    }
  }
  if (t == 1023) row_ptr[N_NODES] = part[1023];
}

__global__ __launch_bounds__(256) void fill_kernel(const int* __restrict__ recv,
                                                   int* __restrict__ cursor,
                                                   int* __restrict__ edge_list) {
  int e = blockIdx.x * 256 + threadIdx.x;
  if (e < N_EDGES) {
    int r = recv[e];
    int pos = atomicAdd(&cursor[r], 1);
    edge_list[pos] = e;
  }
}

// ---------------------------------------------------------------------------
// Fused 2-layer MLP + LayerNorm, wave-local (no __syncthreads).
// Each wave handles 16 rows end-to-end. Block = 4 waves = 64 rows.
// MODE 0: node encoder  (x=[M,11] normalized, K1=32)  -> node_lat
// MODE 1: edge encoder  (x=[M,5]  normalized, K1=32)  -> edge_lat
// MODE 2: edge block    (gather concat, K1=384)       -> edge_lat += y; new_e = y (bf16)
// MODE 3: node block    (node_lat | CSR-sum(new_e), K1=256) -> node_lat += y
// ---------------------------------------------------------------------------
struct MlpArgs {
  const float* x; const float* mean; const float* stdv;
  float* node_lat; float* edge_lat;
  __bf16* new_e;
  const int* senders; const int* receivers;
  const int* row_ptr; const int* edge_list;
  const __bf16* W1t; const __bf16* W2t;
  const float* b1; const float* b2; const float* g; const float* beta;
  int M;
};

template <int K1, int MODE>
__global__ __launch_bounds__(256, 3) void mlp2_kernel(MlpArgs a) {
  constexpr int NKC = K1 / 32;          // A-frag chunks for layer 1
  constexpr int HS  = 136;              // h1 LDS stride (bf16)

  __shared__ __align__(16) __bf16 H1[4 * 16 * HS];   // 17408 B, per-wave strips

  const int tid   = threadIdx.x;
  const int lane  = tid & 63;
  const int wv    = tid >> 6;
  const int l15   = lane & 15;
  const int quad  = lane >> 4;
  const int M     = a.M;
  const int rbase = blockIdx.x * 64 + wv * 16;       // wave's first row
  const int arow  = rbase + l15;                     // row this lane stages
  const int arow_c = (arow < M) ? arow : (M - 1);

  __bf16* h1w = H1 + wv * 16 * HS;

  // ---- stage A fragments straight from global (bf16 in registers) ----
  bf16x8 afrag[NKC];
  if constexpr (MODE == 0 || MODE == 1) {
    constexpr int KIN = (MODE == 0) ? 11 : 5;
    const float* xr = a.x + (size_t)arow_c * KIN;
#pragma unroll
    for (int j = 0; j < 8; ++j) {
      int c = quad * 8 + j;
      float v = (c < KIN) ? (xr[c] - a.mean[c]) / a.stdv[c] : 0.f;
      afrag[0][j] = (__bf16)v;
    }
  } else if constexpr (MODE == 2) {
    const int s = a.senders[arow_c];
    const int r = a.receivers[arow_c];
    const float* pS = a.node_lat + (size_t)s * LDIM + quad * 8;
    const float* pR = a.node_lat + (size_t)r * LDIM + quad * 8;
    const float* pE = a.edge_lat + (size_t)arow_c * LDIM + quad * 8;
#pragma unroll
    for (int kc = 0; kc < 4; ++kc) afrag[kc]     = cvt8(pS + kc * 32);
#pragma unroll
    for (int kc = 0; kc < 4; ++kc) afrag[4 + kc] = cvt8(pR + kc * 32);
#pragma unroll
    for (int kc = 0; kc < 4; ++kc) afrag[8 + kc] = cvt8(pE + kc * 32);
  } else {  // MODE 3: [node_lat | aggr], aggr = CSR-sum of new_e in registers
    const float* pN = a.node_lat + (size_t)arow_c * LDIM + quad * 8;
#pragma unroll
    for (int kc = 0; kc < 4; ++kc) afrag[kc] = cvt8(pN + kc * 32);

    float s[4][8];
#pragma unroll
    for (int kc = 0; kc < 4; ++kc)
#pragma unroll
      for (int j = 0; j < 8; ++j) s[kc][j] = 0.f;

    int p  = a.row_ptr[arow_c];
    const int pe = a.row_ptr[arow_c + 1];
    while (__any(p < pe)) {
      if (p < pe) {
        const int e = a.edge_list[p];
        const __bf16* er = a.new_e + (size_t)e * LDIM + quad * 8;
#pragma unroll
        for (int kc = 0; kc < 4; ++kc) {
          bf16x8 v = *(const bf16x8*)(er + kc * 32);
#pragma unroll
          for (int j = 0; j < 8; ++j) s[kc][j] += (float)v[j];
        }
      }
      ++p;
    }
#pragma unroll
    for (int kc = 0; kc < 4; ++kc)
#pragma unroll
      for (int j = 0; j < 8; ++j) afrag[4 + kc][j] = (__bf16)s[kc][j];
  }

  // ---- layer 1: [16,K1] x [K1,128] per wave ----
  f32x4 acc[8];
#pragma unroll
  for (int i = 0; i < 8; ++i) acc[i] = (f32x4)(0.f);
#pragma unroll
  for (int kc = 0; kc < NKC; ++kc) {
#pragma unroll
    for (int ct = 0; ct < 8; ++ct) {
      bf16x8 bf = *(const bf16x8*)(a.W1t + (ct * 16 + l15) * K1 + kc * 32 + quad * 8);
      acc[ct] = __builtin_amdgcn_mfma_f32_16x16x32_bf16(afrag[kc], bf, acc[ct], 0, 0, 0);
    }
  }

  // ---- h1 = relu(acc+b1) -> per-wave LDS strip (C/D layout -> row-major) ----
#pragma unroll
  for (int ct = 0; ct < 8; ++ct) {
    const float bb = a.b1[ct * 16 + l15];
#pragma unroll
    for (int rr = 0; rr < 4; ++rr) {
      float v = fmaxf(acc[ct][rr] + bb, 0.f);
      h1w[(quad * 4 + rr) * HS + ct * 16 + l15] = (__bf16)v;
    }
  }
  // same-wave DS ordering: write->read in order; compiler inserts lgkmcnt waits.

  // ---- layer 2: [16,128] x [128,128] per wave ----
#pragma unroll
  for (int i = 0; i < 8; ++i) acc[i] = (f32x4)(0.f);
#pragma unroll
  for (int kc = 0; kc < 4; ++kc) {
    bf16x8 af = *(const bf16x8*)(h1w + l15 * HS + kc * 32 + quad * 8);
#pragma unroll
    for (int ct = 0; ct < 8; ++ct) {
      bf16x8 bf = *(const bf16x8*)(a.W2t + (ct * 16 + l15) * LDIM + kc * 32 + quad * 8);
      acc[ct] = __builtin_amdgcn_mfma_f32_16x16x32_bf16(af, bf, acc[ct], 0, 0, 0);
    }
  }

  // ---- h2 = relu(acc+b2), LayerNorm in registers (shuffle over 16 lanes) ----
#pragma unroll
  for (int ct = 0; ct < 8; ++ct) {
    const float bb = a.b2[ct * 16 + l15];
#pragma unroll
    for (int rr = 0; rr < 4; ++rr)
      acc[ct][rr] = fmaxf(acc[ct][rr] + bb, 0.f);
  }

  float mu[4], rs[4];
#pragma unroll
  for (int rr = 0; rr < 4; ++rr) {
    float s = 0.f, s2 = 0.f;
#pragma unroll
    for (int ct = 0; ct < 8; ++ct) { float v = acc[ct][rr]; s += v; s2 += v * v; }
    s  += __shfl_xor(s, 1);  s2 += __shfl_xor(s2, 1);
    s  += __shfl_xor(s, 2);  s2 += __shfl_xor(s2, 2);
    s  += __shfl_xor(s, 4);  s2 += __shfl_xor(s2, 4);
    s  += __shfl_xor(s, 8);  s2 += __shfl_xor(s2, 8);
    float m = s * (1.f / 128.f);
    float var = fmaxf(s2 * (1.f / 128.f) - m * m, 0.f);
    mu[rr] = m; rs[rr] = rsqrtf(var + 1e-5f);
  }

  float gv[8], bev[8];
#pragma unroll
  for (int ct = 0; ct < 8; ++ct) {
    gv[ct]  = a.g[ct * 16 + l15];
    bev[ct] = a.beta[ct * 16 + l15];
  }

  // ---- epilogue (per-wave, guarded rows) ----
#pragma unroll
  for (int rr = 0; rr < 4; ++rr) {
    const int row = rbase + quad * 4 + rr;
    if (row >= M) continue;
    if constexpr (MODE == 2) {
#pragma unroll
      for (int ct = 0; ct < 8; ++ct) {
        const int col = ct * 16 + l15;
        float y = (acc[ct][rr] - mu[rr]) * rs[rr] * gv[ct] + bev[ct];
        a.edge_lat[(size_t)row * LDIM + col] += y;                 // residual
        a.new_e[(size_t)row * LDIM + col] = (__bf16)y;             // for CSR sum
      }
    } else {
#pragma unroll
      for (int ct = 0; ct < 8; ++ct) {
        const int col = ct * 16 + l15;
        float y = (acc[ct][rr] - mu[rr]) * rs[rr] * gv[ct] + bev[ct];
        if constexpr (MODE == 0)      a.node_lat[(size_t)row * LDIM + col] = y;
        else if constexpr (MODE == 1) a.edge_lat[(size_t)row * LDIM + col] = y;
        else                          a.node_lat[(size_t)row * LDIM + col] += y;
      }
    }
  }
}

// ---------------------------------------------------------------------------
// Decoder: h = swish(node_lat @ W1 + b1); dec = h @ W2 + b2; out[t,n] = dec*dt
// ---------------------------------------------------------------------------
__global__ __launch_bounds__(256) void decode_kernel(
    const float* __restrict__ node_lat,
    const float* __restrict__ W1, const float* __restrict__ b1,
    const float* __restrict__ W2, const float* __restrict__ b2,
    float* __restrict__ out) {
  __shared__ float X[64][129];
  const int n0 = blockIdx.x * 64;
  for (int idx = threadIdx.x; idx < 64 * 32; idx += 256) {
    int r = idx >> 5, c4 = idx & 31;
    int n = n0 + r; if (n >= N_NODES) n = N_NODES - 1;
    float4 v = *((const float4*)(node_lat + (size_t)n * 128) + c4);
    X[r][c4 * 4 + 0] = v.x; X[r][c4 * 4 + 1] = v.y;
    X[r][c4 * 4 + 2] = v.z; X[r][c4 * 4 + 3] = v.w;
  }
  __syncthreads();
  const int r = threadIdx.x;
  if (r < 64) {
    const int n = n0 + r;
    if (n < N_NODES) {
      float h[8];
#pragma unroll
      for (int j = 0; j < 8; ++j) h[j] = b1[j];
      for (int k = 0; k < 128; ++k) {
        float xv = X[r][k];
#pragma unroll
        for (int j = 0; j < 8; ++j) h[j] = fmaf(xv, W1[k * 8 + j], h[j]);
      }
#pragma unroll
      for (int j = 0; j < 8; ++j) h[j] = h[j] / (1.f + expf(-h[j]));  // swish
#pragma unroll
      for (int t = 0; t < 5; ++t) {
        float d = b2[t];
#pragma unroll
        for (int j = 0; j < 8; ++j) d = fmaf(h[j], W2[j * 5 + t], d);
        out[t * N_NODES + n] = d * (float)(t + 1);
      }
    }
  }
}

// ---------------------------------------------------------------------------
extern "C" void kernel_launch(void* const* d_in, const int* in_sizes, int n_in,
                              void* d_out, int out_size, void* d_ws, size_t ws_size,
                              hipStream_t stream) {
  (void)in_sizes; (void)n_in; (void)out_size; (void)ws_size;

  const float* node_features = (const float*)d_in[0];
  const float* edge_features = (const float*)d_in[1];
  const int*   senders       = (const int*)d_in[2];
  const int*   receivers     = (const int*)d_in[3];
  const float* node_mean = (const float*)d_in[4];
  const float* node_std  = (const float*)d_in[5];
  const float* edge_mean = (const float*)d_in[6];
  const float* edge_std  = (const float*)d_in[7];
  const float* enc_n_W1 = (const float*)d_in[8];
  const float* enc_n_b1 = (const float*)d_in[9];
  const float* enc_n_W2 = (const float*)d_in[10];
  const float* enc_n_b2 = (const float*)d_in[11];
  const float* enc_n_g    = (const float*)d_in[12];
  const float* enc_n_beta = (const float*)d_in[13];
  const float* enc_e_W1 = (const float*)d_in[14];
  const float* enc_e_b1 = (const float*)d_in[15];
  const float* enc_e_W2 = (const float*)d_in[16];
  const float* enc_e_b2 = (const float*)d_in[17];
  const float* enc_e_g    = (const float*)d_in[18];
  const float* enc_e_beta = (const float*)d_in[19];
  const float* blk_e_W1 = (const float*)d_in[20];
  const float* blk_e_b1 = (const float*)d_in[21];
  const float* blk_e_W2 = (const float*)d_in[22];
  const float* blk_e_b2 = (const float*)d_in[23];
  const float* blk_e_g    = (const float*)d_in[24];
  const float* blk_e_beta = (const float*)d_in[25];
  const float* blk_n_W1 = (const float*)d_in[26];
  const float* blk_n_b1 = (const float*)d_in[27];
  const float* blk_n_W2 = (const float*)d_in[28];
  const float* blk_n_b2 = (const float*)d_in[29];
  const float* blk_n_g    = (const float*)d_in[30];
  const float* blk_n_beta = (const float*)d_in[31];
  const float* dec_W1 = (const float*)d_in[32];
  const float* dec_b1 = (const float*)d_in[33];
  const float* dec_W2 = (const float*)d_in[34];
  const float* dec_b2 = (const float*)d_in[35];

  // ---- workspace layout (bytes, all 16B-aligned) ----
  char* ws = (char*)d_ws;
  float*  node_lat = (float*)(ws);                   // 10,240,000
  float*  edge_lat = (float*)(ws + 10240000);        // 51,200,000
  __bf16* new_e    = (__bf16*)(ws + 61440000);       // 25,600,000 (bf16 E x 128)
  __bf16* wb       = (__bf16*)(ws + 87040000);       // 1,458,176 (bf16 weights)
  int* counts    = (int*)(ws + 88498176);            // 80,000
  int* row_ptr   = (int*)(ws + 88578176);            // 80,004
  int* cursor    = (int*)(ws + 88658192);            // 80,000
  int* edge_list = (int*)(ws + 88738192);            // 400,000 -> ends 89,138,192

  __bf16* enW1t = wb;                    // 128*32
  __bf16* enW2t = enW1t + 4096;          // 128*128
  __bf16* eeW1t = enW2t + 16384;         // 128*32
  __bf16* eeW2t = eeW1t + 4096;          // 128*128
  __bf16* beW1t = eeW2t + 16384;         // 6*128*384
  __bf16* beW2t = beW1t + 6 * 49152;     // 6*128*128
  __bf16* bnW1t = beW2t + 6 * 16384;     // 6*128*256
  __bf16* bnW2t = bnW1t + 6 * 32768;     // 6*128*128

  // ---- prep: weight transpose/convert + zero CSR counts ----
  PrepArgs pa;
  pa.s_enW1 = enc_n_W1; pa.s_enW2 = enc_n_W2; pa.s_eeW1 = enc_e_W1; pa.s_eeW2 = enc_e_W2;
  pa.s_beW1 = blk_e_W1; pa.s_beW2 = blk_e_W2; pa.s_bnW1 = blk_n_W1; pa.s_bnW2 = blk_n_W2;
  pa.d_enW1 = enW1t; pa.d_enW2 = enW2t; pa.d_eeW1 = eeW1t; pa.d_eeW2 = eeW2t;
  pa.d_beW1 = beW1t; pa.d_beW2 = beW2t; pa.d_bnW1 = bnW1t; pa.d_bnW2 = bnW2t;
  pa.counts = counts;
  prep_kernel<<<2927, 256, 0, stream>>>(pa);   // 729,088 weight elems + 20,000

  // ---- CSR build ----
  hist_kernel<<<(N_EDGES + 255) / 256, 256, 0, stream>>>(receivers, counts);
  scan_kernel<<<1, 1024, 0, stream>>>(counts, row_ptr, cursor);
  fill_kernel<<<(N_EDGES + 255) / 256, 256, 0, stream>>>(receivers, cursor, edge_list);

  const int NODE_BLOCKS = (N_NODES + 63) / 64;   // 313
  const int EDGE_BLOCKS = (N_EDGES + 63) / 64;   // 1563

  MlpArgs base;
  base.node_lat = node_lat; base.edge_lat = edge_lat; base.new_e = new_e;
  base.senders = senders; base.receivers = receivers;
  base.row_ptr = row_ptr; base.edge_list = edge_list;
  base.x = nullptr; base.mean = nullptr; base.stdv = nullptr;

  // ---- encoders ----
  {
    MlpArgs a = base;
    a.x = node_features; a.mean = node_mean; a.stdv = node_std;
    a.W1t = enW1t; a.W2t = enW2t;
    a.b1 = enc_n_b1; a.b2 = enc_n_b2; a.g = enc_n_g; a.beta = enc_n_beta;
    a.M = N_NODES;
    mlp2_kernel<32, 0><<<NODE_BLOCKS, 256, 0, stream>>>(a);
  }
  {
    MlpArgs a = base;
    a.x = edge_features; a.mean = edge_mean; a.stdv = edge_std;
    a.W1t = eeW1t; a.W2t = eeW2t;
    a.b1 = enc_e_b1; a.b2 = enc_e_b2; a.g = enc_e_g; a.beta = enc_e_beta;
    a.M = N_EDGES;
    mlp2_kernel<32, 1><<<EDGE_BLOCKS, 256, 0, stream>>>(a);
  }

  // ---- message-passing steps ----
  for (int i = 0; i < NSTEPS; ++i) {
    {
      MlpArgs a = base;
      a.W1t = beW1t + (size_t)i * 49152; a.W2t = beW2t + (size_t)i * 16384;
      a.b1 = blk_e_b1 + i * 128; a.b2 = blk_e_b2 + i * 128;
      a.g = blk_e_g + i * 128; a.beta = blk_e_beta + i * 128;
      a.M = N_EDGES;
      mlp2_kernel<384, 2><<<EDGE_BLOCKS, 256, 0, stream>>>(a);
    }
    {
      MlpArgs a = base;
      a.W1t = bnW1t + (size_t)i * 32768; a.W2t = bnW2t + (size_t)i * 16384;
      a.b1 = blk_n_b1 + i * 128; a.b2 = blk_n_b2 + i * 128;
      a.g = blk_n_g + i * 128; a.beta = blk_n_beta + i * 128;
      a.M = N_NODES;
      mlp2_kernel<256, 3><<<NODE_BLOCKS, 256, 0, stream>>>(a);
    }
  }

  // ---- decoder ----
  decode_kernel<<<NODE_BLOCKS, 256, 0, stream>>>(
      node_lat, dec_W1, dec_b1, dec_W2, dec_b2, (float*)d_out);
}

// Round 5
// 1036.039 us; speedup vs baseline: 1.4819x; 1.1968x over previous
//
#include <hip/hip_runtime.h>
#include <cstdint>
#include <cstddef>

// ---------------------------------------------------------------------------
// EncodeProcessDecode (MeshGraphNets-style GNN) on gfx950.
// N=20000 nodes, E=100000 edges, L=128, S=6 steps.
// Round 5 = Round 4 + grid fix: decode_kernel processes 64 nodes/block and
// needs its own block count (r4 reused the 128-row mlp NODE_BLOCKS=157 ->
// nodes 10048..19999 never written -> absmax 33.25).
// Round 4 change under test: register blocking. r3 counters showed
// VGPR_Count=60 -> compiler serialized every weight load (vmcnt(0) before
// each MFMA). Each wave owns 32 rows (2 row-tiles); per K-chunk load
// 2 A-frags + 8 B-frags into named registers, then 16 MFMAs -> each B-load
// feeds 2 MFMAs and loads pipeline across chunks. CSR aggr (MODE 3) stages
// through the per-wave LDS strip (wave-local in-order DS, no barriers).
// ---------------------------------------------------------------------------

#define N_NODES 20000
#define N_EDGES 100000
#define LDIM    128
#define NSTEPS  6

typedef float  f32x4  __attribute__((ext_vector_type(4)));
typedef __bf16 bf16x8 __attribute__((ext_vector_type(8)));

// load 8 consecutive fp32, round to bf16x8 (one MFMA A-frag chunk)
__device__ __forceinline__ bf16x8 cvt8(const float* p) {
  float4 u = *(const float4*)p;
  float4 v = *(const float4*)(p + 4);
  bf16x8 o;
  o[0] = (__bf16)u.x; o[1] = (__bf16)u.y; o[2] = (__bf16)u.z; o[3] = (__bf16)u.w;
  o[4] = (__bf16)v.x; o[5] = (__bf16)v.y; o[6] = (__bf16)v.z; o[7] = (__bf16)v.w;
  return o;
}

// ---------------------------------------------------------------------------
// Prep kernel: fp32 -> bf16 transpose of all MLP weights into d_ws,
// + zero CSR counts. Layout of each dst: Wt[col][k] row-major, k padded.
// ---------------------------------------------------------------------------
struct PrepArgs {
  const float *s_enW1, *s_enW2, *s_eeW1, *s_eeW2;
  const float *s_beW1, *s_beW2, *s_bnW1, *s_bnW2;
  __bf16 *d_enW1, *d_enW2, *d_eeW1, *d_eeW2;
  __bf16 *d_beW1, *d_beW2, *d_bnW1, *d_bnW2;
  int* counts;
};

__global__ __launch_bounds__(256) void prep_kernel(PrepArgs p) {
  int idx = blockIdx.x * 256 + threadIdx.x;

  if (idx < 4096) {                    // enc_n_W1t [128][32], src [11][128]
    int c = idx >> 5, k = idx & 31;
    p.d_enW1[idx] = (__bf16)((k < 11) ? p.s_enW1[k * 128 + c] : 0.f);
    return;
  }
  idx -= 4096;
  if (idx < 16384) {                   // enc_n_W2t [128][128]
    int c = idx >> 7, k = idx & 127;
    p.d_enW2[idx] = (__bf16)p.s_enW2[k * 128 + c];
    return;
  }
  idx -= 16384;
  if (idx < 4096) {                    // enc_e_W1t [128][32], src [5][128]
    int c = idx >> 5, k = idx & 31;
    p.d_eeW1[idx] = (__bf16)((k < 5) ? p.s_eeW1[k * 128 + c] : 0.f);
    return;
  }
  idx -= 4096;
  if (idx < 16384) {                   // enc_e_W2t
    int c = idx >> 7, k = idx & 127;
    p.d_eeW2[idx] = (__bf16)p.s_eeW2[k * 128 + c];
    return;
  }
  idx -= 16384;
  if (idx < 294912) {                  // blk_e_W1t [6][128][384], src [6][384][128]
    int s = idx / 49152, rem = idx % 49152;
    int c = rem / 384, k = rem % 384;
    p.d_beW1[idx] = (__bf16)p.s_beW1[(size_t)s * 49152 + k * 128 + c];
    return;
  }
  idx -= 294912;
  if (idx < 98304) {                   // blk_e_W2t [6][128][128]
    int s = idx >> 14, rem = idx & 16383;
    int c = rem >> 7, k = rem & 127;
    p.d_beW2[idx] = (__bf16)p.s_beW2[s * 16384 + k * 128 + c];
    return;
  }
  idx -= 98304;
  if (idx < 196608) {                  // blk_n_W1t [6][128][256], src [6][256][128]
    int s = idx >> 15, rem = idx & 32767;
    int c = rem >> 8, k = rem & 255;
    p.d_bnW1[idx] = (__bf16)p.s_bnW1[s * 32768 + k * 128 + c];
    return;
  }
  idx -= 196608;
  if (idx < 98304) {                   // blk_n_W2t [6][128][128]
    int s = idx >> 14, rem = idx & 16383;
    int c = rem >> 7, k = rem & 127;
    p.d_bnW2[idx] = (__bf16)p.s_bnW2[s * 16384 + k * 128 + c];
    return;
  }
  idx -= 98304;
  if (idx < N_NODES) p.counts[idx] = 0;   // zero CSR histogram
}

// ---- CSR build: histogram -> scan -> fill -------------------------------
__global__ __launch_bounds__(256) void hist_kernel(const int* __restrict__ recv,
                                                   int* __restrict__ counts) {
  int e = blockIdx.x * 256 + threadIdx.x;
  if (e < N_EDGES) atomicAdd(&counts[recv[e]], 1);
}

__global__ __launch_bounds__(1024) void scan_kernel(const int* __restrict__ counts,
                                                    int* __restrict__ row_ptr,
                                                    int* __restrict__ cursor) {
  __shared__ int part[1024];
  const int t = threadIdx.x;
  const int base = t * 20;
  int local[20];
  int s = 0;
#pragma unroll
  for (int i = 0; i < 20; ++i) {
    int idx = base + i;
    int v = (idx < N_NODES) ? counts[idx] : 0;
    local[i] = s;                      // exclusive within chunk
    s += v;
  }
  part[t] = s;
  __syncthreads();
  for (int off = 1; off < 1024; off <<= 1) {
    int add = (t >= off) ? part[t - off] : 0;
    __syncthreads();
    part[t] += add;
    __syncthreads();
  }
  const int excl = part[t] - s;        // exclusive prefix of this chunk
#pragma unroll
  for (int i = 0; i < 20; ++i) {
    int idx = base + i;
    if (idx < N_NODES) {
      int v = excl + local[i];
      row_ptr[idx] = v;
      cursor[idx]  = v;
    }
  }
  if (t == 1023) row_ptr[N_NODES] = part[1023];
}

__global__ __launch_bounds__(256) void fill_kernel(const int* __restrict__ recv,
                                                   int* __restrict__ cursor,
                                                   int* __restrict__ edge_list) {
  int e = blockIdx.x * 256 + threadIdx.x;
  if (e < N_EDGES) {
    int r = recv[e];
    int pos = atomicAdd(&cursor[r], 1);
    edge_list[pos] = e;
  }
}

// ---------------------------------------------------------------------------
// Fused 2-layer MLP + LayerNorm, wave-local (no __syncthreads).
// Each wave handles 32 rows (2 row-tiles). Block = 4 waves = 128 rows.
// MODE 0: node encoder  (x=[M,11] normalized, K1=32)  -> node_lat
// MODE 1: edge encoder  (x=[M,5]  normalized, K1=32)  -> edge_lat
// MODE 2: edge block    (gather concat, K1=384)       -> edge_lat += y; new_e = y (bf16)
// MODE 3: node block    (node_lat | CSR-sum(new_e), K1=256) -> node_lat += y
// ---------------------------------------------------------------------------
struct MlpArgs {
  const float* x; const float* mean; const float* stdv;
  float* node_lat; float* edge_lat;
  __bf16* new_e;
  const int* senders; const int* receivers;
  const int* row_ptr; const int* edge_list;
  const __bf16* W1t; const __bf16* W2t;
  const float* b1; const float* b2; const float* g; const float* beta;
  int M;
};

template <int K1, int MODE>
__global__ __launch_bounds__(256, 3) void mlp2_kernel(MlpArgs a) {
  constexpr int NKC = K1 / 32;          // K-chunks for layer 1
  constexpr int RT  = 2;                // row-tiles per wave
  constexpr int HS  = 136;              // LDS strip stride (bf16)

  __shared__ __align__(16) __bf16 H1[4 * 32 * HS];   // 34816 B, per-wave strips

  const int tid   = threadIdx.x;
  const int lane  = tid & 63;
  const int wv    = tid >> 6;
  const int l15   = lane & 15;
  const int quad  = lane >> 4;
  const int M     = a.M;
  const int rbase = blockIdx.x * 128 + wv * 32;      // wave's first row

  __bf16* h1w = H1 + wv * 32 * HS;

  // rows this lane stages as A (one per row-tile)
  int rowA[RT];
#pragma unroll
  for (int rt = 0; rt < RT; ++rt) {
    int r = rbase + rt * 16 + l15;
    rowA[rt] = (r < M) ? r : (M - 1);
  }

  int sA[RT], rA[RT];
  if constexpr (MODE == 2) {
#pragma unroll
    for (int rt = 0; rt < RT; ++rt) {
      sA[rt] = a.senders[rowA[rt]];
      rA[rt] = a.receivers[rowA[rt]];
    }
  }

  if constexpr (MODE == 3) {
    // ---- CSR-sum new_e into the LDS strip (acts as aggr staging) ----
#pragma unroll
    for (int rt = 0; rt < RT; ++rt) {
      float s[4][8];
#pragma unroll
      for (int kc = 0; kc < 4; ++kc)
#pragma unroll
        for (int j = 0; j < 8; ++j) s[kc][j] = 0.f;
      int p  = a.row_ptr[rowA[rt]];
      const int pe = a.row_ptr[rowA[rt] + 1];
      while (__any(p < pe)) {
        if (p < pe) {
          const int e = a.edge_list[p];
          const __bf16* er = a.new_e + (size_t)e * LDIM + quad * 8;
#pragma unroll
          for (int kc = 0; kc < 4; ++kc) {
            bf16x8 v = *(const bf16x8*)(er + kc * 32);
#pragma unroll
            for (int j = 0; j < 8; ++j) s[kc][j] += (float)v[j];
          }
        }
        ++p;
      }
#pragma unroll
      for (int kc = 0; kc < 4; ++kc) {
        bf16x8 o;
#pragma unroll
        for (int j = 0; j < 8; ++j) o[j] = (__bf16)s[kc][j];
        *(bf16x8*)(h1w + (rt * 16 + l15) * HS + kc * 32 + quad * 8) = o;
      }
    }
  }

  f32x4 acc[RT][8];
#pragma unroll
  for (int rt = 0; rt < RT; ++rt)
#pragma unroll
    for (int i = 0; i < 8; ++i) acc[rt][i] = (f32x4)(0.f);

  // ---- layer 1: [32,K1] x [K1,128] per wave, batched loads per K-chunk ----
#pragma unroll
  for (int kc = 0; kc < NKC; ++kc) {
    bf16x8 af[RT];
    if constexpr (MODE == 0 || MODE == 1) {
      constexpr int KIN = (MODE == 0) ? 11 : 5;
#pragma unroll
      for (int rt = 0; rt < RT; ++rt) {
        const float* xr = a.x + (size_t)rowA[rt] * KIN;
#pragma unroll
        for (int j = 0; j < 8; ++j) {
          int c = quad * 8 + j;
          float v = (c < KIN) ? (xr[c] - a.mean[c]) / a.stdv[c] : 0.f;
          af[rt][j] = (__bf16)v;
        }
      }
    } else if constexpr (MODE == 2) {
      if (kc < 4) {
#pragma unroll
        for (int rt = 0; rt < RT; ++rt)
          af[rt] = cvt8(a.node_lat + (size_t)sA[rt] * LDIM + kc * 32 + quad * 8);
      } else if (kc < 8) {
#pragma unroll
        for (int rt = 0; rt < RT; ++rt)
          af[rt] = cvt8(a.node_lat + (size_t)rA[rt] * LDIM + (kc - 4) * 32 + quad * 8);
      } else {
#pragma unroll
        for (int rt = 0; rt < RT; ++rt)
          af[rt] = cvt8(a.edge_lat + (size_t)rowA[rt] * LDIM + (kc - 8) * 32 + quad * 8);
      }
    } else {  // MODE 3
      if (kc < 4) {
#pragma unroll
        for (int rt = 0; rt < RT; ++rt)
          af[rt] = cvt8(a.node_lat + (size_t)rowA[rt] * LDIM + kc * 32 + quad * 8);
      } else {
#pragma unroll
        for (int rt = 0; rt < RT; ++rt)
          af[rt] = *(const bf16x8*)(h1w + (rt * 16 + l15) * HS + (kc - 4) * 32 + quad * 8);
      }
    }

    bf16x8 bf[8];
#pragma unroll
    for (int ct = 0; ct < 8; ++ct)
      bf[ct] = *(const bf16x8*)(a.W1t + (ct * 16 + l15) * K1 + kc * 32 + quad * 8);

#pragma unroll
    for (int rt = 0; rt < RT; ++rt)
#pragma unroll
      for (int ct = 0; ct < 8; ++ct)
        acc[rt][ct] = __builtin_amdgcn_mfma_f32_16x16x32_bf16(af[rt], bf[ct], acc[rt][ct], 0, 0, 0);
  }

  // ---- h1 = relu(acc+b1) -> per-wave LDS strip (C/D layout -> row-major) ----
#pragma unroll
  for (int ct = 0; ct < 8; ++ct) {
    const float bb = a.b1[ct * 16 + l15];
#pragma unroll
    for (int rt = 0; rt < RT; ++rt)
#pragma unroll
      for (int rr = 0; rr < 4; ++rr) {
        float v = fmaxf(acc[rt][ct][rr] + bb, 0.f);
        h1w[(rt * 16 + quad * 4 + rr) * HS + ct * 16 + l15] = (__bf16)v;
      }
  }
  // same-wave DS ordering: writes before reads in program order.

  // ---- layer 2: [32,128] x [128,128] per wave ----
#pragma unroll
  for (int rt = 0; rt < RT; ++rt)
#pragma unroll
    for (int i = 0; i < 8; ++i) acc[rt][i] = (f32x4)(0.f);

#pragma unroll
  for (int kc = 0; kc < 4; ++kc) {
    bf16x8 af[RT];
#pragma unroll
    for (int rt = 0; rt < RT; ++rt)
      af[rt] = *(const bf16x8*)(h1w + (rt * 16 + l15) * HS + kc * 32 + quad * 8);
    bf16x8 bf[8];
#pragma unroll
    for (int ct = 0; ct < 8; ++ct)
      bf[ct] = *(const bf16x8*)(a.W2t + (ct * 16 + l15) * LDIM + kc * 32 + quad * 8);
#pragma unroll
    for (int rt = 0; rt < RT; ++rt)
#pragma unroll
      for (int ct = 0; ct < 8; ++ct)
        acc[rt][ct] = __builtin_amdgcn_mfma_f32_16x16x32_bf16(af[rt], bf[ct], acc[rt][ct], 0, 0, 0);
  }

  // ---- h2 = relu(acc+b2), LayerNorm in registers (shuffle over 16 lanes) ----
#pragma unroll
  for (int ct = 0; ct < 8; ++ct) {
    const float bb = a.b2[ct * 16 + l15];
#pragma unroll
    for (int rt = 0; rt < RT; ++rt)
#pragma unroll
      for (int rr = 0; rr < 4; ++rr)
        acc[rt][ct][rr] = fmaxf(acc[rt][ct][rr] + bb, 0.f);
  }

  float mu[RT][4], rs[RT][4];
#pragma unroll
  for (int rt = 0; rt < RT; ++rt)
#pragma unroll
    for (int rr = 0; rr < 4; ++rr) {
      float s = 0.f, s2 = 0.f;
#pragma unroll
      for (int ct = 0; ct < 8; ++ct) { float v = acc[rt][ct][rr]; s += v; s2 += v * v; }
      s  += __shfl_xor(s, 1);  s2 += __shfl_xor(s2, 1);
      s  += __shfl_xor(s, 2);  s2 += __shfl_xor(s2, 2);
      s  += __shfl_xor(s, 4);  s2 += __shfl_xor(s2, 4);
      s  += __shfl_xor(s, 8);  s2 += __shfl_xor(s2, 8);
      float m = s * (1.f / 128.f);
      float var = fmaxf(s2 * (1.f / 128.f) - m * m, 0.f);
      mu[rt][rr] = m; rs[rt][rr] = rsqrtf(var + 1e-5f);
    }

  float gv[8], bev[8];
#pragma unroll
  for (int ct = 0; ct < 8; ++ct) {
    gv[ct]  = a.g[ct * 16 + l15];
    bev[ct] = a.beta[ct * 16 + l15];
  }

  // ---- epilogue (per-wave, guarded rows) ----
#pragma unroll
  for (int rt = 0; rt < RT; ++rt)
#pragma unroll
    for (int rr = 0; rr < 4; ++rr) {
      const int row = rbase + rt * 16 + quad * 4 + rr;
      if (row >= M) continue;
      if constexpr (MODE == 2) {
#pragma unroll
        for (int ct = 0; ct < 8; ++ct) {
          const int col = ct * 16 + l15;
          float y = (acc[rt][ct][rr] - mu[rt][rr]) * rs[rt][rr] * gv[ct] + bev[ct];
          a.edge_lat[(size_t)row * LDIM + col] += y;                 // residual
          a.new_e[(size_t)row * LDIM + col] = (__bf16)y;             // for CSR sum
        }
      } else {
#pragma unroll
        for (int ct = 0; ct < 8; ++ct) {
          const int col = ct * 16 + l15;
          float y = (acc[rt][ct][rr] - mu[rt][rr]) * rs[rt][rr] * gv[ct] + bev[ct];
          if constexpr (MODE == 0)      a.node_lat[(size_t)row * LDIM + col] = y;
          else if constexpr (MODE == 1) a.edge_lat[(size_t)row * LDIM + col] = y;
          else                          a.node_lat[(size_t)row * LDIM + col] += y;
        }
      }
    }
}

// ---------------------------------------------------------------------------
// Decoder: h = swish(node_lat @ W1 + b1); dec = h @ W2 + b2; out[t,n] = dec*dt
// Processes 64 nodes per block -> needs its own grid size (DEC_BLOCKS).
// ---------------------------------------------------------------------------
__global__ __launch_bounds__(256) void decode_kernel(
    const float* __restrict__ node_lat,
    const float* __restrict__ W1, const float* __restrict__ b1,
    const float* __restrict__ W2, const float* __restrict__ b2,
    float* __restrict__ out) {
  __shared__ float X[64][129];
  const int n0 = blockIdx.x * 64;
  for (int idx = threadIdx.x; idx < 64 * 32; idx += 256) {
    int r = idx >> 5, c4 = idx & 31;
    int n = n0 + r; if (n >= N_NODES) n = N_NODES - 1;
    float4 v = *((const float4*)(node_lat + (size_t)n * 128) + c4);
    X[r][c4 * 4 + 0] = v.x; X[r][c4 * 4 + 1] = v.y;
    X[r][c4 * 4 + 2] = v.z; X[r][c4 * 4 + 3] = v.w;
  }
  __syncthreads();
  const int r = threadIdx.x;
  if (r < 64) {
    const int n = n0 + r;
    if (n < N_NODES) {
      float h[8];
#pragma unroll
      for (int j = 0; j < 8; ++j) h[j] = b1[j];
      for (int k = 0; k < 128; ++k) {
        float xv = X[r][k];
#pragma unroll
        for (int j = 0; j < 8; ++j) h[j] = fmaf(xv, W1[k * 8 + j], h[j]);
      }
#pragma unroll
      for (int j = 0; j < 8; ++j) h[j] = h[j] / (1.f + expf(-h[j]));  // swish
#pragma unroll
      for (int t = 0; t < 5; ++t) {
        float d = b2[t];
#pragma unroll
        for (int j = 0; j < 8; ++j) d = fmaf(h[j], W2[j * 5 + t], d);
        out[t * N_NODES + n] = d * (float)(t + 1);
      }
    }
  }
}

// ---------------------------------------------------------------------------
extern "C" void kernel_launch(void* const* d_in, const int* in_sizes, int n_in,
                              void* d_out, int out_size, void* d_ws, size_t ws_size,
                              hipStream_t stream) {
  (void)in_sizes; (void)n_in; (void)out_size; (void)ws_size;

  const float* node_features = (const float*)d_in[0];
  const float* edge_features = (const float*)d_in[1];
  const int*   senders       = (const int*)d_in[2];
  const int*   receivers     = (const int*)d_in[3];
  const float* node_mean = (const float*)d_in[4];
  const float* node_std  = (const float*)d_in[5];
  const float* edge_mean = (const float*)d_in[6];
  const float* edge_std  = (const float*)d_in[7];
  const float* enc_n_W1 = (const float*)d_in[8];
  const float* enc_n_b1 = (const float*)d_in[9];
  const float* enc_n_W2 = (const float*)d_in[10];
  const float* enc_n_b2 = (const float*)d_in[11];
  const float* enc_n_g    = (const float*)d_in[12];
  const float* enc_n_beta = (const float*)d_in[13];
  const float* enc_e_W1 = (const float*)d_in[14];
  const float* enc_e_b1 = (const float*)d_in[15];
  const float* enc_e_W2 = (const float*)d_in[16];
  const float* enc_e_b2 = (const float*)d_in[17];
  const float* enc_e_g    = (const float*)d_in[18];
  const float* enc_e_beta = (const float*)d_in[19];
  const float* blk_e_W1 = (const float*)d_in[20];
  const float* blk_e_b1 = (const float*)d_in[21];
  const float* blk_e_W2 = (const float*)d_in[22];
  const float* blk_e_b2 = (const float*)d_in[23];
  const float* blk_e_g    = (const float*)d_in[24];
  const float* blk_e_beta = (const float*)d_in[25];
  const float* blk_n_W1 = (const float*)d_in[26];
  const float* blk_n_b1 = (const float*)d_in[27];
  const float* blk_n_W2 = (const float*)d_in[28];
  const float* blk_n_b2 = (const float*)d_in[29];
  const float* blk_n_g    = (const float*)d_in[30];
  const float* blk_n_beta = (const float*)d_in[31];
  const float* dec_W1 = (const float*)d_in[32];
  const float* dec_b1 = (const float*)d_in[33];
  const float* dec_W2 = (const float*)d_in[34];
  const float* dec_b2 = (const float*)d_in[35];

  // ---- workspace layout (bytes, all 16B-aligned) ----
  char* ws = (char*)d_ws;
  float*  node_lat = (float*)(ws);                   // 10,240,000
  float*  edge_lat = (float*)(ws + 10240000);        // 51,200,000
  __bf16* new_e    = (__bf16*)(ws + 61440000);       // 25,600,000 (bf16 E x 128)
  __bf16* wb       = (__bf16*)(ws + 87040000);       // 1,458,176 (bf16 weights)
  int* counts    = (int*)(ws + 88498176);            // 80,000
  int* row_ptr   = (int*)(ws + 88578176);            // 80,004
  int* cursor    = (int*)(ws + 88658192);            // 80,000
  int* edge_list = (int*)(ws + 88738192);            // 400,000 -> ends 89,138,192

  __bf16* enW1t = wb;                    // 128*32
  __bf16* enW2t = enW1t + 4096;          // 128*128
  __bf16* eeW1t = enW2t + 16384;         // 128*32
  __bf16* eeW2t = eeW1t + 4096;          // 128*128
  __bf16* beW1t = eeW2t + 16384;         // 6*128*384
  __bf16* beW2t = beW1t + 6 * 49152;     // 6*128*128
  __bf16* bnW1t = beW2t + 6 * 16384;     // 6*128*256
  __bf16* bnW2t = bnW1t + 6 * 32768;     // 6*128*128

  // ---- prep: weight transpose/convert + zero CSR counts ----
  PrepArgs pa;
  pa.s_enW1 = enc_n_W1; pa.s_enW2 = enc_n_W2; pa.s_eeW1 = enc_e_W1; pa.s_eeW2 = enc_e_W2;
  pa.s_beW1 = blk_e_W1; pa.s_beW2 = blk_e_W2; pa.s_bnW1 = blk_n_W1; pa.s_bnW2 = blk_n_W2;
  pa.d_enW1 = enW1t; pa.d_enW2 = enW2t; pa.d_eeW1 = eeW1t; pa.d_eeW2 = eeW2t;
  pa.d_beW1 = beW1t; pa.d_beW2 = beW2t; pa.d_bnW1 = bnW1t; pa.d_bnW2 = bnW2t;
  pa.counts = counts;
  prep_kernel<<<2927, 256, 0, stream>>>(pa);   // 729,088 weight elems + 20,000

  // ---- CSR build ----
  hist_kernel<<<(N_EDGES + 255) / 256, 256, 0, stream>>>(receivers, counts);
  scan_kernel<<<1, 1024, 0, stream>>>(counts, row_ptr, cursor);
  fill_kernel<<<(N_EDGES + 255) / 256, 256, 0, stream>>>(receivers, cursor, edge_list);

  const int NODE_BLOCKS = (N_NODES + 127) / 128;   // 157 (mlp2: 128 rows/block)
  const int EDGE_BLOCKS = (N_EDGES + 127) / 128;   // 782
  const int DEC_BLOCKS  = (N_NODES + 63) / 64;     // 313 (decode: 64 rows/block)

  MlpArgs base;
  base.node_lat = node_lat; base.edge_lat = edge_lat; base.new_e = new_e;
  base.senders = senders; base.receivers = receivers;
  base.row_ptr = row_ptr; base.edge_list = edge_list;
  base.x = nullptr; base.mean = nullptr; base.stdv = nullptr;

  // ---- encoders ----
  {
    MlpArgs a = base;
    a.x = node_features; a.mean = node_mean; a.stdv = node_std;
    a.W1t = enW1t; a.W2t = enW2t;
    a.b1 = enc_n_b1; a.b2 = enc_n_b2; a.g = enc_n_g; a.beta = enc_n_beta;
    a.M = N_NODES;
    mlp2_kernel<32, 0><<<NODE_BLOCKS, 256, 0, stream>>>(a);
  }
  {
    MlpArgs a = base;
    a.x = edge_features; a.mean = edge_mean; a.stdv = edge_std;
    a.W1t = eeW1t; a.W2t = eeW2t;
    a.b1 = enc_e_b1; a.b2 = enc_e_b2; a.g = enc_e_g; a.beta = enc_e_beta;
    a.M = N_EDGES;
    mlp2_kernel<32, 1><<<EDGE_BLOCKS, 256, 0, stream>>>(a);
  }

  // ---- message-passing steps ----
  for (int i = 0; i < NSTEPS; ++i) {
    {
      MlpArgs a = base;
      a.W1t = beW1t + (size_t)i * 49152; a.W2t = beW2t + (size_t)i * 16384;
      a.b1 = blk_e_b1 + i * 128; a.b2 = blk_e_b2 + i * 128;
      a.g = blk_e_g + i * 128; a.beta = blk_e_beta + i * 128;
      a.M = N_EDGES;
      mlp2_kernel<384, 2><<<EDGE_BLOCKS, 256, 0, stream>>>(a);
    }
    {
      MlpArgs a = base;
      a.W1t = bnW1t + (size_t)i * 32768; a.W2t = bnW2t + (size_t)i * 16384;
      a.b1 = blk_n_b1 + i * 128; a.b2 = blk_n_b2 + i * 128;
      a.g = blk_n_g + i * 128; a.beta = blk_n_beta + i * 128;
      a.M = N_NODES;
      mlp2_kernel<256, 3><<<NODE_BLOCKS, 256, 0, stream>>>(a);
    }
  }

  // ---- decoder ----
  decode_kernel<<<DEC_BLOCKS, 256, 0, stream>>>(
      node_lat, dec_W1, dec_b1, dec_W2, dec_b2, (float*)d_out);
}